// Round 1
// baseline (745.780 us; speedup 1.0000x reference)
//
#include <hip/hip_runtime.h>
#include <hip/hip_fp16.h>

// LogSpaceSinkhorn: 64 matrices of 1024x1024 fp32.
// Potentials-only formulation, FUSED column+row passes:
//   Each block owns a 64-col x 1024-row stripe (full columns!), so after
//   computing its stripe's col LSEs c_j it can emit per-stripe partial row
//   sums P[mat][stripe][row] = sum_{j in stripe} exp(t - c_j) in the same
//   kernel, reading the stripe from LDS (cached during sweep 1).
//   Next kernel's prologue: r_i = log(sum_s P[s][i])  (exact: the
//   potentials recurrence r_{k+1} = LSE_j(t - c_k) absorbs old r).
// 7 dispatches instead of 12; t read-passes 11 -> 6.

#define NROWS 1024
#define NCOLS 1024
#define NMAT 64
#define MATELEMS (NROWS * NCOLS)
#define NSTRIPE 16  // 64-col stripes per matrix
#define SCOLS 64    // cols per stripe
#define SH8 8       // H8 (8-half) groups per stripe row

struct __align__(16) H8 { __half2 h[4]; };  // 16 bytes = 8 halves

__device__ __forceinline__ float wave_sum(float v) {
#pragma unroll
  for (int o = 32; o > 0; o >>= 1) v += __shfl_xor(v, o, 64);
  return v;
}

// Pass 1: t = x*it stored as fp16; S[row] = sum_j exp(t) (plain sum, not log
// -- downstream prologue takes the log). One wave per row, 4 rows per block.
__global__ __launch_bounds__(256) void convert_row(
    const float* __restrict__ x, __half* __restrict__ t,
    float* __restrict__ S, const float* __restrict__ tau) {
  const float it = 1.0f / fmaxf(tau[0], 0.1f);
  const int row = blockIdx.x * 4 + (threadIdx.x >> 6);
  const int lane = threadIdx.x & 63;
  const float4* xr = (const float4*)(x + (size_t)row * NCOLS);
  H8* tr = (H8*)(t + (size_t)row * NCOLS);
  float s = 0.0f;
#pragma unroll
  for (int k = 0; k < 2; ++k) {
    const int f4 = k * 128 + lane * 2;  // float4 index in row
    float4 a = xr[f4];
    float4 b = xr[f4 + 1];
    a.x *= it; a.y *= it; a.z *= it; a.w *= it;
    b.x *= it; b.y *= it; b.z *= it; b.w *= it;
    H8 o;
    o.h[0] = __floats2half2_rn(a.x, a.y);
    o.h[1] = __floats2half2_rn(a.z, a.w);
    o.h[2] = __floats2half2_rn(b.x, b.y);
    o.h[3] = __floats2half2_rn(b.z, b.w);
    tr[k * 64 + lane] = o;
    s += __expf(a.x) + __expf(a.y) + __expf(a.z) + __expf(a.w) +
         __expf(b.x) + __expf(b.y) + __expf(b.z) + __expf(b.w);
  }
  s = wave_sum(s);
  if (lane == 0) S[row] = s;
}

// Fused iteration kernel. One block per (matrix, 64-col stripe), 1024 threads.
// LDS: 128 KB swizzled stripe + 4 KB r + 4 KB reduce scratch (~136.5 KB,
// 1 block/CU, 16 waves -- sweep 1 is the only global phase and stays BW-fed).
// Prologue: r_i = log(sum_{s<ns} Pin[mat][s][i])           (row potentials)
// Sweep 1 : stage stripe -> LDS (XOR swizzle slot = c8^(row&7)) while
//           colsum_j = sum_i exp(t_ij - r_i); c_j = log(colsum) -> cout
// Sweep 2 : FINAL=0: Pout[mat][sb][row] = sum_{j in stripe} exp(t_ij - c_j)
//           FINAL=1: out_ij = exp(t_ij - r_i - 0.5*(cin_j + c_j))
template <int FINAL>
__global__ __launch_bounds__(1024) void fused_col(
    const __half* __restrict__ t, const float* __restrict__ Pin, const int ns,
    const float* __restrict__ cin, float* __restrict__ cout,
    float* __restrict__ Pout, float* __restrict__ out) {
  const int mat = blockIdx.x >> 4;
  const int sb = blockIdx.x & 15;
  const int tid = threadIdx.x;
  const __half* tb = t + (size_t)mat * MATELEMS + sb * SCOLS;

  __shared__ H8 tile[NROWS * SH8];   // 128 KB, XOR-swizzled
  __shared__ float r_lds[NROWS];     // 4 KB
  __shared__ float wred[16][SCOLS];  // 4 KB per-wave col partials
  __shared__ float c_lds[SCOLS];     // c_j (or h_j = 0.5*(cin+e) when FINAL)

  // Prologue: row potentials from partial sums of previous dispatch.
  {
    const float* pb = Pin + (size_t)mat * ns * NROWS + tid;
    float acc = 0.0f;
    for (int s2 = 0; s2 < ns; ++s2) acc += pb[s2 * NROWS];
    r_lds[tid] = __logf(acc);
  }
  __syncthreads();

  // Sweep 1: global -> LDS staging + column sums.
  const int c8 = tid & 7;     // H8 group within stripe row
  const int rowg = tid >> 3;  // 0..127
  float s[8];
#pragma unroll
  for (int j = 0; j < 8; ++j) s[j] = 0.0f;
#pragma unroll
  for (int ch = 0; ch < 8; ++ch) {
    const int row = ch * 128 + rowg;
    H8 v = ((const H8*)(tb + (size_t)row * NCOLS))[c8];
    tile[row * SH8 + (c8 ^ (row & 7))] = v;  // swizzled store
    const float ri = r_lds[row];
    float2 f0 = __half22float2(v.h[0]);
    float2 f1 = __half22float2(v.h[1]);
    float2 f2 = __half22float2(v.h[2]);
    float2 f3 = __half22float2(v.h[3]);
    s[0] += __expf(f0.x - ri); s[1] += __expf(f0.y - ri);
    s[2] += __expf(f1.x - ri); s[3] += __expf(f1.y - ri);
    s[4] += __expf(f2.x - ri); s[5] += __expf(f2.y - ri);
    s[6] += __expf(f3.x - ri); s[7] += __expf(f3.y - ri);
  }
  // In-wave reduce over the 8 row-groups (lane bits 3..5).
#pragma unroll
  for (int j = 0; j < 8; ++j) {
    s[j] += __shfl_xor(s[j], 8, 64);
    s[j] += __shfl_xor(s[j], 16, 64);
    s[j] += __shfl_xor(s[j], 32, 64);
  }
  if ((tid & 63) < 8) {  // lane == c8 for lanes 0..7
    const int wv = tid >> 6;
#pragma unroll
    for (int j = 0; j < 8; ++j) wred[wv][c8 * 8 + j] = s[j];
  }
  __syncthreads();
  if (tid < SCOLS) {
    float acc = 0.0f;
#pragma unroll
    for (int w = 0; w < 16; ++w) acc += wred[w][tid];
    const float lse = __logf(acc);
    if (FINAL) {
      c_lds[tid] = 0.5f * (lse + cin[mat * NCOLS + sb * SCOLS + tid]);
    } else {
      c_lds[tid] = lse;
      cout[mat * NCOLS + sb * SCOLS + tid] = lse;
    }
  }
  __syncthreads();

  if (!FINAL) {
    // Sweep 2: one thread per row; whole row-stripe is thread-local, so the
    // partial row sum needs no cross-lane reduce. Conflict-free via swizzle.
    const int row = tid;
    const int sw = row & 7;
    float rp0 = 0.0f, rp1 = 0.0f;
#pragma unroll
    for (int g = 0; g < 8; ++g) {
      H8 v = tile[row * SH8 + (g ^ sw)];  // physical g^sw holds logical g
      float2 f0 = __half22float2(v.h[0]);
      float2 f1 = __half22float2(v.h[1]);
      float2 f2 = __half22float2(v.h[2]);
      float2 f3 = __half22float2(v.h[3]);
      const float* cj = &c_lds[g * 8];
      rp0 += __expf(f0.x - cj[0]) + __expf(f0.y - cj[1]) +
             __expf(f1.x - cj[2]) + __expf(f1.y - cj[3]);
      rp1 += __expf(f2.x - cj[4]) + __expf(f2.y - cj[5]) +
             __expf(f3.x - cj[6]) + __expf(f3.y - cj[7]);
    }
    Pout[((size_t)mat * NSTRIPE + sb) * NROWS + row] = rp0 + rp1;
  } else {
    // Sweep 2 (final): write output; mapping chosen for 256B write segments.
    const int colh = tid & 7;
    const int rg = tid >> 3;
    float h[8];
#pragma unroll
    for (int j = 0; j < 8; ++j) h[j] = c_lds[colh * 8 + j];
    float* ob = out + (size_t)mat * MATELEMS + sb * SCOLS;
#pragma unroll
    for (int ch = 0; ch < 8; ++ch) {
      const int row = ch * 128 + rg;
      H8 v = tile[row * SH8 + (colh ^ (row & 7))];
      const float ri = r_lds[row];
      float2 f0 = __half22float2(v.h[0]);
      float2 f1 = __half22float2(v.h[1]);
      float2 f2 = __half22float2(v.h[2]);
      float2 f3 = __half22float2(v.h[3]);
      float4 o0, o1;
      o0.x = __expf(f0.x - ri - h[0]);
      o0.y = __expf(f0.y - ri - h[1]);
      o0.z = __expf(f1.x - ri - h[2]);
      o0.w = __expf(f1.y - ri - h[3]);
      o1.x = __expf(f2.x - ri - h[4]);
      o1.y = __expf(f2.y - ri - h[5]);
      o1.z = __expf(f3.x - ri - h[6]);
      o1.w = __expf(f3.y - ri - h[7]);
      float4* op = (float4*)(ob + (size_t)row * NCOLS) + colh * 2;
      op[0] = o0;
      op[1] = o1;
    }
  }
}

extern "C" void kernel_launch(void* const* d_in, const int* in_sizes, int n_in,
                              void* d_out, int out_size, void* d_ws,
                              size_t ws_size, hipStream_t stream) {
  const float* x = (const float*)d_in[0];
  const float* tau = (const float*)d_in[1];
  float* out = (float*)d_out;

  __half* t = (__half*)d_ws;  // 128 MB fp16 matrix cache
  float* S1 = (float*)((char*)d_ws + (size_t)NMAT * MATELEMS * sizeof(__half));
  float* PA = S1 + NMAT * NROWS;           // 4 MB row-partial ping
  float* PB = PA + NMAT * NSTRIPE * NROWS; // 4 MB row-partial pong
  float* c = PB + NMAT * NSTRIPE * NROWS;  // 256 KB col potentials

  const int row_grid = NMAT * NROWS / 4;  // 16384
  const int f_grid = NMAT * NSTRIPE;      // 1024

  // r1 partials (ns=1)
  convert_row<<<row_grid, 256, 0, stream>>>(x, t, S1, tau);
  // 5 Sinkhorn iterations: c_k from r_k, and partials for r_{k+1}.
  fused_col<0><<<f_grid, 1024, 0, stream>>>(t, S1, 1, nullptr, c, PA, nullptr);
  fused_col<0><<<f_grid, 1024, 0, stream>>>(t, PA, NSTRIPE, nullptr, c, PB, nullptr);
  fused_col<0><<<f_grid, 1024, 0, stream>>>(t, PB, NSTRIPE, nullptr, c, PA, nullptr);
  fused_col<0><<<f_grid, 1024, 0, stream>>>(t, PA, NSTRIPE, nullptr, c, PB, nullptr);
  fused_col<0><<<f_grid, 1024, 0, stream>>>(t, PB, NSTRIPE, nullptr, c, PA, nullptr);
  // Final: r6 = log(sum PA); e = colLSE(t - r6); out = exp(t - r6 - 0.5*(c5+e))
  fused_col<1><<<f_grid, 1024, 0, stream>>>(t, PA, NSTRIPE, c, nullptr, nullptr, out);
}

// Round 2
// 709.899 us; speedup vs baseline: 1.0505x; 1.0505x over previous
//
#include <hip/hip_runtime.h>
#include <hip/hip_fp16.h>

// LogSpaceSinkhorn: 64 matrices of 1024x1024 fp32.
// MULTIPLICATIVE Sinkhorn: cache K = exp(x/tau) once as fp16 (uniform 2^-11
// rel error -- better than fp16 t, whose rounding costs ~2e-3 rel after exp).
// Every pass is then a positive accumulation (cvt+fma per element, NO exp):
//   R_i = sum_j K_ij * iC_j   (row sums;  u_i = 1/R_i)
//   C_j = sum_i K_ij * u_i    (col sums; iC_j = 1/C_j)
//   out = K_ij * u6_i * w_j,  w_j = rsqrt(C5_j * E_j)
// Global shift a = max(0, 6/tau - 10) guards fp16 overflow for small tau;
// it cancels exactly (only R is shifted, C/E/out are shift-invariant).
// Per-element transcendentals: 870M -> 67M (convert only).
//
// Fused stripe kernel (unchanged structure): block owns a 64-col x 1024-row
// stripe, stages it in LDS during the col-sum sweep, then emits per-stripe
// partial ROW sums from LDS -- next kernel's prologue finishes u = 1/sum.
// 7 dispatches; t read-passes 6.

#define NROWS 1024
#define NCOLS 1024
#define NMAT 64
#define MATELEMS (NROWS * NCOLS)
#define NSTRIPE 16  // 64-col stripes per matrix
#define SCOLS 64    // cols per stripe
#define SH8 8       // H8 (8-half) groups per stripe row

struct __align__(16) H8 { __half2 h[4]; };  // 16 bytes = 8 halves

__device__ __forceinline__ float wave_sum(float v) {
#pragma unroll
  for (int o = 32; o > 0; o >>= 1) v += __shfl_xor(v, o, 64);
  return v;
}

// Pass 1: K = exp(x*it - a) stored fp16; S[row] = sum_j K (plain sum).
// One wave per row, 4 rows per 256-thread block.
__global__ __launch_bounds__(256) void convert_row(
    const float* __restrict__ x, __half* __restrict__ t,
    float* __restrict__ S, const float* __restrict__ tau) {
  const float it = 1.0f / fmaxf(tau[0], 0.1f);
  const float sh = fmaxf(0.0f, 6.0f * it - 10.0f);  // fp16-overflow guard
  const int row = blockIdx.x * 4 + (threadIdx.x >> 6);
  const int lane = threadIdx.x & 63;
  const float4* xr = (const float4*)(x + (size_t)row * NCOLS);
  H8* tr = (H8*)(t + (size_t)row * NCOLS);
  float s = 0.0f;
#pragma unroll
  for (int k = 0; k < 2; ++k) {
    const int f4 = k * 128 + lane * 2;  // float4 index in row
    float4 va = xr[f4];
    float4 vb = xr[f4 + 1];
    float e0 = __expf(va.x * it - sh);
    float e1 = __expf(va.y * it - sh);
    float e2 = __expf(va.z * it - sh);
    float e3 = __expf(va.w * it - sh);
    float e4 = __expf(vb.x * it - sh);
    float e5 = __expf(vb.y * it - sh);
    float e6 = __expf(vb.z * it - sh);
    float e7 = __expf(vb.w * it - sh);
    H8 o;
    o.h[0] = __floats2half2_rn(e0, e1);
    o.h[1] = __floats2half2_rn(e2, e3);
    o.h[2] = __floats2half2_rn(e4, e5);
    o.h[3] = __floats2half2_rn(e6, e7);
    tr[k * 64 + lane] = o;
    s += e0 + e1 + e2 + e3 + e4 + e5 + e6 + e7;
  }
  s = wave_sum(s);
  if (lane == 0) S[row] = s;
}

// Fused iteration kernel. One block per (matrix, 64-col stripe), 1024 threads.
// Prologue: u_i = 1 / sum_{s<ns} Pin[mat][s][i]            (row scale)
// Sweep 1 : stage stripe -> LDS (XOR swizzle) while C_j = sum_i K_ij * u_i
//           FINAL=0: cout_j = C_j, c_lds = 1/C_j
//           FINAL=1: c_lds = w_j = rsqrt(C_j * cin_j)
// Sweep 2 : FINAL=0: Pout[mat][sb][row] = sum_{j in stripe} K_ij / C_j
//           FINAL=1: out_ij = K_ij * u_i * w_j
template <int FINAL>
__global__ __launch_bounds__(1024) void fused_col(
    const __half* __restrict__ t, const float* __restrict__ Pin, const int ns,
    const float* __restrict__ cin, float* __restrict__ cout,
    float* __restrict__ Pout, float* __restrict__ out) {
  const int mat = blockIdx.x >> 4;
  const int sb = blockIdx.x & 15;
  const int tid = threadIdx.x;
  const __half* tb = t + (size_t)mat * MATELEMS + sb * SCOLS;

  __shared__ H8 tile[NROWS * SH8];   // 128 KB, XOR-swizzled
  __shared__ float r_lds[NROWS];     // 4 KB (u_i)
  __shared__ float wred[16][SCOLS];  // 4 KB per-wave col partials
  __shared__ float c_lds[SCOLS];     // iC_j (or w_j when FINAL)

  // Prologue: row scales from partial sums of previous dispatch.
  {
    const float* pb = Pin + (size_t)mat * ns * NROWS + tid;
    float acc = 0.0f;
    for (int s2 = 0; s2 < ns; ++s2) acc += pb[s2 * NROWS];
    r_lds[tid] = 1.0f / acc;
  }
  __syncthreads();

  // Sweep 1: global -> LDS staging + column sums.
  const int c8 = tid & 7;     // H8 group within stripe row
  const int rowg = tid >> 3;  // 0..127
  float s[8];
#pragma unroll
  for (int j = 0; j < 8; ++j) s[j] = 0.0f;
#pragma unroll
  for (int ch = 0; ch < 8; ++ch) {
    const int row = ch * 128 + rowg;
    H8 v = ((const H8*)(tb + (size_t)row * NCOLS))[c8];
    tile[row * SH8 + (c8 ^ (row & 7))] = v;  // swizzled store
    const float ui = r_lds[row];
    float2 f0 = __half22float2(v.h[0]);
    float2 f1 = __half22float2(v.h[1]);
    float2 f2 = __half22float2(v.h[2]);
    float2 f3 = __half22float2(v.h[3]);
    s[0] += f0.x * ui; s[1] += f0.y * ui;
    s[2] += f1.x * ui; s[3] += f1.y * ui;
    s[4] += f2.x * ui; s[5] += f2.y * ui;
    s[6] += f3.x * ui; s[7] += f3.y * ui;
  }
  // In-wave reduce over the 8 row-groups (lane bits 3..5).
#pragma unroll
  for (int j = 0; j < 8; ++j) {
    s[j] += __shfl_xor(s[j], 8, 64);
    s[j] += __shfl_xor(s[j], 16, 64);
    s[j] += __shfl_xor(s[j], 32, 64);
  }
  if ((tid & 63) < 8) {  // lane == c8 for lanes 0..7
    const int wv = tid >> 6;
#pragma unroll
    for (int j = 0; j < 8; ++j) wred[wv][c8 * 8 + j] = s[j];
  }
  __syncthreads();
  if (tid < SCOLS) {
    float acc = 0.0f;
#pragma unroll
    for (int w = 0; w < 16; ++w) acc += wred[w][tid];
    if (FINAL) {
      // acc = E_j; cin = C5_j; w_j = 1/sqrt(E*C5)
      c_lds[tid] = 1.0f / sqrtf(acc * cin[mat * NCOLS + sb * SCOLS + tid]);
    } else {
      cout[mat * NCOLS + sb * SCOLS + tid] = acc;  // C_j
      c_lds[tid] = 1.0f / acc;                     // iC_j
    }
  }
  __syncthreads();

  if (!FINAL) {
    // Sweep 2: one thread per row; whole row-stripe is thread-local.
    const int row = tid;
    const int sw = row & 7;
    float rp0 = 0.0f, rp1 = 0.0f;
#pragma unroll
    for (int g = 0; g < 8; ++g) {
      H8 v = tile[row * SH8 + (g ^ sw)];  // physical g^sw holds logical g
      float2 f0 = __half22float2(v.h[0]);
      float2 f1 = __half22float2(v.h[1]);
      float2 f2 = __half22float2(v.h[2]);
      float2 f3 = __half22float2(v.h[3]);
      const float* cj = &c_lds[g * 8];
      rp0 += f0.x * cj[0] + f0.y * cj[1] + f1.x * cj[2] + f1.y * cj[3];
      rp1 += f2.x * cj[4] + f2.y * cj[5] + f3.x * cj[6] + f3.y * cj[7];
    }
    Pout[((size_t)mat * NSTRIPE + sb) * NROWS + row] = rp0 + rp1;
  } else {
    // Sweep 2 (final): out = K * u_i * w_j; 256B write segments.
    const int colh = tid & 7;
    const int rg = tid >> 3;
    float h[8];
#pragma unroll
    for (int j = 0; j < 8; ++j) h[j] = c_lds[colh * 8 + j];
    float* ob = out + (size_t)mat * MATELEMS + sb * SCOLS;
#pragma unroll
    for (int ch = 0; ch < 8; ++ch) {
      const int row = ch * 128 + rg;
      H8 v = tile[row * SH8 + (colh ^ (row & 7))];
      const float ui = r_lds[row];
      float2 f0 = __half22float2(v.h[0]);
      float2 f1 = __half22float2(v.h[1]);
      float2 f2 = __half22float2(v.h[2]);
      float2 f3 = __half22float2(v.h[3]);
      float4 o0, o1;
      o0.x = f0.x * ui * h[0];
      o0.y = f0.y * ui * h[1];
      o0.z = f1.x * ui * h[2];
      o0.w = f1.y * ui * h[3];
      o1.x = f2.x * ui * h[4];
      o1.y = f2.y * ui * h[5];
      o1.z = f3.x * ui * h[6];
      o1.w = f3.y * ui * h[7];
      float4* op = (float4*)(ob + (size_t)row * NCOLS) + colh * 2;
      op[0] = o0;
      op[1] = o1;
    }
  }
}

extern "C" void kernel_launch(void* const* d_in, const int* in_sizes, int n_in,
                              void* d_out, int out_size, void* d_ws,
                              size_t ws_size, hipStream_t stream) {
  const float* x = (const float*)d_in[0];
  const float* tau = (const float*)d_in[1];
  float* out = (float*)d_out;

  __half* t = (__half*)d_ws;  // 128 MB fp16 K cache
  float* S1 = (float*)((char*)d_ws + (size_t)NMAT * MATELEMS * sizeof(__half));
  float* PA = S1 + NMAT * NROWS;           // 4 MB row-partial ping
  float* PB = PA + NMAT * NSTRIPE * NROWS; // 4 MB row-partial pong
  float* c = PB + NMAT * NSTRIPE * NROWS;  // 256 KB col sums C_j

  const int row_grid = NMAT * NROWS / 4;  // 16384
  const int f_grid = NMAT * NSTRIPE;      // 1024

  // K and R1 partials (ns=1)
  convert_row<<<row_grid, 256, 0, stream>>>(x, t, S1, tau);
  // 5 Sinkhorn iterations: C_k from u_k, and partials for R_{k+1}.
  fused_col<0><<<f_grid, 1024, 0, stream>>>(t, S1, 1, nullptr, c, PA, nullptr);
  fused_col<0><<<f_grid, 1024, 0, stream>>>(t, PA, NSTRIPE, nullptr, c, PB, nullptr);
  fused_col<0><<<f_grid, 1024, 0, stream>>>(t, PB, NSTRIPE, nullptr, c, PA, nullptr);
  fused_col<0><<<f_grid, 1024, 0, stream>>>(t, PA, NSTRIPE, nullptr, c, PB, nullptr);
  fused_col<0><<<f_grid, 1024, 0, stream>>>(t, PB, NSTRIPE, nullptr, c, PA, nullptr);
  // Final: u6 from PA; E = colsum(K*u6); out = K * u6 * rsqrt(C5*E)
  fused_col<1><<<f_grid, 1024, 0, stream>>>(t, PA, NSTRIPE, c, nullptr, nullptr, out);
}